// Round 4
// baseline (174.366 us; speedup 1.0000x reference)
//
#include <hip/hip_runtime.h>

typedef __attribute__((ext_vector_type(8))) short bf16x8;
typedef __attribute__((ext_vector_type(4))) float f32x4;

namespace {

constexpr int B = 32, T = 128, V = 128, F = 64, O = 64;
constexpr int TPB = 4;   // t-tiles per block; grid = (T/TPB, B) = 1024 blocks

// ws layout (bytes): [Acat bf16 B*128*256][ThT bf16 192*64][ldiag f32 B*128]
constexpr size_t WS_THT_OFF = (size_t)B * V * 256 * 2;      // 2 MiB
constexpr size_t WS_LDG_OFF = WS_THT_OFF + 192 * 64 * 2;    // +24 KiB

__device__ inline unsigned short f2bf(float f) {
    unsigned u = __builtin_bit_cast(unsigned, f);
    u += 0x7FFFu + ((u >> 16) & 1u);
    return (unsigned short)(u >> 16);
}

// ---------------- prep: build Acat (zero-diag, bf16), ThT (bf16), ldiag (f32) ----------------
__global__ __launch_bounds__(256) void prep(const float* __restrict__ W,
                                            const float* __restrict__ Theta,
                                            unsigned short* __restrict__ acat,
                                            unsigned short* __restrict__ tht,
                                            float* __restrict__ ldg) {
    const int tid = threadIdx.x;
    if (blockIdx.x == B) {
        // ThT[n][f]: n in [0,192) = [Th0-Th2 | Th1 | Th2] columns, f in [0,64)
        for (int i = 0; i < 192 * 64 / 256; ++i) {
            int idx = tid + i * 256;
            int n = idx >> 6, f = idx & 63;
            float v;
            if (n < 64)       v = Theta[f * 64 + n] - Theta[2 * 4096 + f * 64 + n];
            else if (n < 128) v = Theta[4096 + f * 64 + (n - 64)];
            else              v = Theta[2 * 4096 + f * 64 + (n - 128)];
            tht[idx] = f2bf(v);
        }
        return;
    }
    const int b = blockIdx.x;
    const float* Wb = W + (size_t)b * V * V;
    __shared__ float Wl[V][V + 1];
    for (int i = 0; i < V * V / 256; ++i) {
        int idx = tid + i * 256;
        Wl[idx >> 7][idx & 127] = Wb[idx];
    }
    __syncthreads();
    if (tid < V) {
        float s = 0.f;
        for (int i = 0; i < V; ++i) s += Wl[i][tid];       // deg[u] = sum_i W[i][u]
        ldg[b * V + tid] = s - 1.0f - Wl[tid][tid];        // ldiag
    }
    unsigned short* ab = acat + (size_t)b * V * 256;
    for (int i = 0; i < V; ++i) {
        int idx = tid + i * 256;
        int u = idx >> 8, kv = idx & 255, v = kv & 127;
        float wv = Wl[v][u];
        float val = (v == u) ? 0.f : ((kv < 128) ? -wv : 2.f * wv * wv);
        ab[idx] = f2bf(val);
    }
}

// ---------------- main: per (b, 4 t's), software-pipelined over t ----------------
__global__ __launch_bounds__(256, 2) void graph_conv_main(
    const float* __restrict__ x, const unsigned short* __restrict__ acat,
    const unsigned short* __restrict__ tht_g, const float* __restrict__ ldg,
    float* __restrict__ out) {
    const int t0 = blockIdx.x * TPB, b = blockIdx.y;
    const int tid = threadIdx.x;
    const int lane = tid & 63, w = tid >> 6;
    const int lr = lane & 15, lg = lane >> 4;

    // Separate buffers (no aliasing): th persists across the t-loop.
    __shared__ __align__(16) unsigned short th[192 * 64];   // 24 KB
    __shared__ __align__(16) unsigned short xs[V * F];      // 16 KB
    __shared__ __align__(16) unsigned short zct[64 * 256];  // 32 KB
    __shared__ __align__(16) float ldg_s[V];
    // total 72.5 KB -> 2 blocks/CU

    const float* xb = x + ((size_t)(b * T + t0)) * (V * F);

    // ---- prologue: issue x(t0) loads (coalesced float4), stage th, ldg ----
    float4 pf[8];
#pragma unroll
    for (int i = 0; i < 8; ++i) pf[i] = ((const float4*)xb)[tid + i * 256];

#pragma unroll
    for (int i = 0; i < 6; ++i) {
        int c = tid + i * 256;                 // 1536 16B-chunks of ThT
        int row = c >> 3, c8 = c & 7;
        uint4 val = *(const uint4*)(tht_g + row * 64 + c8 * 8);
        int off = row * 128 + ((c8 * 16) ^ ((row & 7) << 4));
        *(uint4*)((char*)th + off) = val;
    }
    if (tid < V) ldg_s[tid] = ldg[b * V + tid];

    // convert pf -> xs for t0
#pragma unroll
    for (int i = 0; i < 8; ++i) {
        int p = tid + i * 256;                 // float4 index in 128x64 tile
        int row = p >> 4, c4 = p & 15;
        uint2 q;
        q.x = f2bf(pf[i].x) | ((unsigned)f2bf(pf[i].y) << 16);
        q.y = f2bf(pf[i].z) | ((unsigned)f2bf(pf[i].w) << 16);
        *(uint2*)((char*)xs + row * 128 + ((c4 * 8) ^ ((row & 7) << 4))) = q;
    }
    __syncthreads();

    const unsigned short* ab = acat + (size_t)b * V * 256;

    for (int tt = 0; tt < TPB; ++tt) {
        // ---- issue prefetch of x(tt+1) early: hides under Z-phase MFMAs ----
        if (tt + 1 < TPB) {
            const float4* nxt = (const float4*)(xb + (size_t)(tt + 1) * (V * F));
#pragma unroll
            for (int i = 0; i < 8; ++i) pf[i] = nxt[tid + i * 256];
        }

        // ---- Z phase: rows v in [32w, 32w+32). acc gets Zm; z[][0..3]=Z1, z[][4..7]=Z2 ----
        f32x4 acc[2][4];
        f32x4 z[2][8];
#pragma unroll
        for (int vf = 0; vf < 2; ++vf) {
#pragma unroll
            for (int of = 0; of < 4; ++of) acc[vf][of] = (f32x4){0.f, 0.f, 0.f, 0.f};
#pragma unroll
            for (int nf = 0; nf < 8; ++nf) z[vf][nf] = (f32x4){0.f, 0.f, 0.f, 0.f};
        }
#pragma unroll
        for (int ks = 0; ks < 2; ++ks) {
            bf16x8 xa[2];
#pragma unroll
            for (int vf = 0; vf < 2; ++vf) {
                int row = w * 32 + 16 * vf + lr;
                int off = row * 128 + ((ks * 64 + lg * 16) ^ ((row & 7) << 4));
                xa[vf] = *(const bf16x8*)((const char*)xs + off);
            }
#pragma unroll
            for (int nf = 0; nf < 12; ++nf) {
                int rowt = nf * 16 + lr;
                int off = rowt * 128 + ((ks * 64 + lg * 16) ^ ((rowt & 7) << 4));
                bf16x8 tb = *(const bf16x8*)((const char*)th + off);
                if (nf < 4) {
                    acc[0][nf] = __builtin_amdgcn_mfma_f32_16x16x32_bf16(xa[0], tb, acc[0][nf], 0, 0, 0);
                    acc[1][nf] = __builtin_amdgcn_mfma_f32_16x16x32_bf16(xa[1], tb, acc[1][nf], 0, 0, 0);
                } else {
                    z[0][nf - 4] = __builtin_amdgcn_mfma_f32_16x16x32_bf16(xa[0], tb, z[0][nf - 4], 0, 0, 0);
                    z[1][nf - 4] = __builtin_amdgcn_mfma_f32_16x16x32_bf16(xa[1], tb, z[1][nf - 4], 0, 0, 0);
                }
            }
        }

        // ---- fp32 diagonal term (v-slab == u-slab, register-local) ----
#pragma unroll
        for (int vf = 0; vf < 2; ++vf) {
            f32x4 ld = *(const f32x4*)(ldg_s + w * 32 + 16 * vf + lg * 4);
            f32x4 ld2 = 2.0f * ld * ld;
#pragma unroll
            for (int of = 0; of < 4; ++of)
                acc[vf][of] += ld * z[vf][of] + ld2 * z[vf][4 + of];
        }

        __syncthreads();   // barrier1: xs reads (Z) + prev contraction zct reads done

        // ---- write ZcatT[o][kv] bf16 (o-major, swizzled) ----
#pragma unroll
        for (int vf = 0; vf < 2; ++vf) {
            int vcol = w * 32 + 16 * vf + lg * 4;
#pragma unroll
            for (int of = 0; of < 4; ++of) {
                int rowz = of * 16 + lr;
                f32x4 z1 = z[vf][of], z2 = z[vf][4 + of];
                uint2 q1, q2;
                q1.x = f2bf(z1[0]) | ((unsigned)f2bf(z1[1]) << 16);
                q1.y = f2bf(z1[2]) | ((unsigned)f2bf(z1[3]) << 16);
                q2.x = f2bf(z2[0]) | ((unsigned)f2bf(z2[1]) << 16);
                q2.y = f2bf(z2[2]) | ((unsigned)f2bf(z2[3]) << 16);
                int base = rowz * 512;
                *(uint2*)((char*)zct + base + (((vcol * 2)) ^ ((rowz & 7) << 4))) = q1;
                *(uint2*)((char*)zct + base + ((256 + vcol * 2) ^ ((rowz & 7) << 4))) = q2;
            }
        }

        // ---- write xs for tt+1 (pf landed during Z-phase) ----
        if (tt + 1 < TPB) {
#pragma unroll
            for (int i = 0; i < 8; ++i) {
                int p = tid + i * 256;
                int row = p >> 4, c4 = p & 15;
                uint2 q;
                q.x = f2bf(pf[i].x) | ((unsigned)f2bf(pf[i].y) << 16);
                q.y = f2bf(pf[i].z) | ((unsigned)f2bf(pf[i].w) << 16);
                *(uint2*)((char*)xs + row * 128 + ((c4 * 8) ^ ((row & 7) << 4))) = q;
            }
        }
        __syncthreads();   // barrier2: zct + xs(tt+1) visible

        // ---- contraction: acc += Acat[u, 0:256] @ Zcat ----
#pragma unroll
        for (int ks = 0; ks < 8; ++ks) {
            bf16x8 af[2];
#pragma unroll
            for (int uf = 0; uf < 2; ++uf) {
                int rowa = w * 32 + 16 * uf + lr;
                af[uf] = *(const bf16x8*)(ab + rowa * 256 + ks * 32 + lg * 8);
            }
#pragma unroll
            for (int of = 0; of < 4; ++of) {
                int rowz = of * 16 + lr;
                int off = rowz * 512 + ((ks * 64 + lg * 16) ^ ((rowz & 7) << 4));
                bf16x8 zb = *(const bf16x8*)((const char*)zct + off);
                acc[0][of] = __builtin_amdgcn_mfma_f32_16x16x32_bf16(af[0], zb, acc[0][of], 0, 0, 0);
                acc[1][of] = __builtin_amdgcn_mfma_f32_16x16x32_bf16(af[1], zb, acc[1][of], 0, 0, 0);
            }
        }

        // ---- epilogue: relu + store t = t0+tt ----
        float* obt = out + ((size_t)(b * T + t0 + tt)) * (V * O);
#pragma unroll
        for (int vf = 0; vf < 2; ++vf)
#pragma unroll
            for (int of = 0; of < 4; ++of)
#pragma unroll
                for (int j = 0; j < 4; ++j) {
                    int u = w * 32 + 16 * vf + lg * 4 + j;
                    int o = of * 16 + lr;
                    float r = acc[vf][of][j];
                    obt[u * 64 + o] = r > 0.f ? r : 0.f;
                }
    }
}

}  // namespace

extern "C" void kernel_launch(void* const* d_in, const int* in_sizes, int n_in,
                              void* d_out, int out_size, void* d_ws, size_t ws_size,
                              hipStream_t stream) {
    const float* x = (const float*)d_in[0];      // (B,T,V,F)
    const float* W = (const float*)d_in[1];      // (B,V,V)
    const float* Theta = (const float*)d_in[2];  // (3,F,O)
    float* outp = (float*)d_out;                 // (B,T,V,O)

    unsigned short* acat = (unsigned short*)d_ws;
    unsigned short* tht = (unsigned short*)((char*)d_ws + WS_THT_OFF);
    float* ldg = (float*)((char*)d_ws + WS_LDG_OFF);

    prep<<<B + 1, 256, 0, stream>>>(W, Theta, acat, tht, ldg);
    graph_conv_main<<<dim3(T / TPB, B), 256, 0, stream>>>(x, acat, tht, ldg, outp);
}

// Round 5
// 128.722 us; speedup vs baseline: 1.3546x; 1.3546x over previous
//
#include <hip/hip_runtime.h>

typedef __attribute__((ext_vector_type(8))) short bf16x8;
typedef __attribute__((ext_vector_type(4))) float f32x4;

namespace {

constexpr int B = 32, T = 128, V = 128, F = 64, O = 64;

// ws layout (bytes): [Acat bf16 B*128*256][ThT bf16 192*64][ldiag f32 B*128]
constexpr size_t WS_THT_OFF = (size_t)B * V * 256 * 2;      // 2 MiB
constexpr size_t WS_LDG_OFF = WS_THT_OFF + 192 * 64 * 2;    // +24 KiB

__device__ inline unsigned short f2bf(float f) {
    unsigned u = __builtin_bit_cast(unsigned, f);
    u += 0x7FFFu + ((u >> 16) & 1u);
    return (unsigned short)(u >> 16);
}

__device__ inline bf16x8 pack8(const float4 a, const float4 b) {
    uint4 u;
    u.x = f2bf(a.x) | ((unsigned)f2bf(a.y) << 16);
    u.y = f2bf(a.z) | ((unsigned)f2bf(a.w) << 16);
    u.z = f2bf(b.x) | ((unsigned)f2bf(b.y) << 16);
    u.w = f2bf(b.z) | ((unsigned)f2bf(b.w) << 16);
    return __builtin_bit_cast(bf16x8, u);
}

// ---------------- prep: build Acat (zero-diag, bf16), ThT (bf16), ldiag (f32) ----------------
__global__ __launch_bounds__(256) void prep(const float* __restrict__ W,
                                            const float* __restrict__ Theta,
                                            unsigned short* __restrict__ acat,
                                            unsigned short* __restrict__ tht,
                                            float* __restrict__ ldg) {
    const int tid = threadIdx.x;
    if (blockIdx.x == B) {
        // ThT[n][f]: n in [0,192) = [Th0-Th2 | Th1 | Th2] columns, f in [0,64)
        for (int i = 0; i < 192 * 64 / 256; ++i) {
            int idx = tid + i * 256;
            int n = idx >> 6, f = idx & 63;
            float v;
            if (n < 64)       v = Theta[f * 64 + n] - Theta[2 * 4096 + f * 64 + n];
            else if (n < 128) v = Theta[4096 + f * 64 + (n - 64)];
            else              v = Theta[2 * 4096 + f * 64 + (n - 128)];
            tht[idx] = f2bf(v);
        }
        return;
    }
    const int b = blockIdx.x;
    const float* Wb = W + (size_t)b * V * V;
    __shared__ float Wl[V][V + 1];
    for (int i = 0; i < V * V / 256; ++i) {
        int idx = tid + i * 256;
        Wl[idx >> 7][idx & 127] = Wb[idx];
    }
    __syncthreads();
    if (tid < V) {
        float s = 0.f;
        for (int i = 0; i < V; ++i) s += Wl[i][tid];       // deg[u] = sum_i W[i][u]
        ldg[b * V + tid] = s - 1.0f - Wl[tid][tid];        // ldiag
    }
    unsigned short* ab = acat + (size_t)b * V * 256;
    for (int i = 0; i < V; ++i) {
        int idx = tid + i * 256;
        int u = idx >> 8, kv = idx & 255, v = kv & 127;
        float wv = Wl[v][u];
        float val = (v == u) ? 0.f : ((kv < 128) ? -wv : 2.f * wv * wv);
        ab[idx] = f2bf(val);
    }
}

// ---------------- main: per (b,t); fragments direct from global; zct is the only LDS ----------------
__global__ __launch_bounds__(256, 3) void graph_conv_main(
    const float* __restrict__ x, const unsigned short* __restrict__ acat,
    const unsigned short* __restrict__ tht_g, const float* __restrict__ ldg,
    float* __restrict__ out) {
    const int t = blockIdx.x, b = blockIdx.y;
    const int tid = threadIdx.x;
    const int lane = tid & 63, w = tid >> 6;
    const int lr = lane & 15, lg = lane >> 4;

    __shared__ __align__(16) unsigned short zct[64 * 256];  // 32 KB, the ONLY LDS buffer

    const float* xbt = x + ((size_t)(b * T + t)) * (V * F);

    // ---- A-fragments of x, direct from global (fp32 -> bf16) ----
    // xa[vf][ks]: row = w*32+16vf+lr, fp32 elems [ks*32+lg*8, +8)
    bf16x8 xa[2][2];
#pragma unroll
    for (int vf = 0; vf < 2; ++vf) {
        const int row = w * 32 + 16 * vf + lr;
#pragma unroll
        for (int ks = 0; ks < 2; ++ks) {
            const float4* p = (const float4*)(xbt + row * 64 + ks * 32 + lg * 8);
            float4 q0 = p[0], q1 = p[1];
            xa[vf][ks] = pack8(q0, q1);
        }
    }

    // ---- Z phase: B-fragments of ThT direct from global (L2-hot 24 KB) ----
    f32x4 acc[2][4];   // Zm accumulates here (k=0 identity term)
    f32x4 z[2][8];     // z[][0..3]=Z1, z[][4..7]=Z2
#pragma unroll
    for (int vf = 0; vf < 2; ++vf) {
#pragma unroll
        for (int of = 0; of < 4; ++of) acc[vf][of] = (f32x4){0.f, 0.f, 0.f, 0.f};
#pragma unroll
        for (int nf = 0; nf < 8; ++nf) z[vf][nf] = (f32x4){0.f, 0.f, 0.f, 0.f};
    }
#pragma unroll
    for (int ks = 0; ks < 2; ++ks) {
#pragma unroll
        for (int nf = 0; nf < 12; ++nf) {
            const int rowt = nf * 16 + lr;
            bf16x8 tb = *(const bf16x8*)(tht_g + rowt * 64 + ks * 32 + lg * 8);
            if (nf < 4) {
                acc[0][nf] = __builtin_amdgcn_mfma_f32_16x16x32_bf16(xa[0][ks], tb, acc[0][nf], 0, 0, 0);
                acc[1][nf] = __builtin_amdgcn_mfma_f32_16x16x32_bf16(xa[1][ks], tb, acc[1][nf], 0, 0, 0);
            } else {
                z[0][nf - 4] = __builtin_amdgcn_mfma_f32_16x16x32_bf16(xa[0][ks], tb, z[0][nf - 4], 0, 0, 0);
                z[1][nf - 4] = __builtin_amdgcn_mfma_f32_16x16x32_bf16(xa[1][ks], tb, z[1][nf - 4], 0, 0, 0);
            }
        }
    }

    // ---- fp32 diagonal term: acc += ldiag*Z1 + 2*ldiag^2*Z2 (v-slab == u-slab, register-local) ----
    const float* ldb = ldg + b * V;
#pragma unroll
    for (int vf = 0; vf < 2; ++vf) {
        f32x4 ld = *(const f32x4*)(ldb + w * 32 + 16 * vf + lg * 4);
        f32x4 ld2 = 2.0f * ld * ld;
#pragma unroll
        for (int of = 0; of < 4; ++of)
            acc[vf][of] += ld * z[vf][of] + ld2 * z[vf][4 + of];
    }

    // ---- write ZcatT[o][kv] bf16 (o-major, swizzled); zct is fresh, no pre-write barrier needed ----
#pragma unroll
    for (int vf = 0; vf < 2; ++vf) {
        const int vcol = w * 32 + 16 * vf + lg * 4;
#pragma unroll
        for (int of = 0; of < 4; ++of) {
            const int rowz = of * 16 + lr;
            f32x4 z1 = z[vf][of], z2 = z[vf][4 + of];
            uint2 q1, q2;
            q1.x = f2bf(z1[0]) | ((unsigned)f2bf(z1[1]) << 16);
            q1.y = f2bf(z1[2]) | ((unsigned)f2bf(z1[3]) << 16);
            q2.x = f2bf(z2[0]) | ((unsigned)f2bf(z2[1]) << 16);
            q2.y = f2bf(z2[2]) | ((unsigned)f2bf(z2[3]) << 16);
            const int base = rowz * 512;
            *(uint2*)((char*)zct + base + (((vcol * 2)) ^ ((rowz & 7) << 4))) = q1;
            *(uint2*)((char*)zct + base + ((256 + vcol * 2) ^ ((rowz & 7) << 4))) = q2;
        }
    }
    __syncthreads();   // the ONLY barrier: zct visible to all waves

    // ---- contraction: acc += Acat[u, 0:256] @ Zcat (A-frags from global, L2-hot 64 KB/batch) ----
    const unsigned short* ab = acat + (size_t)b * V * 256;
#pragma unroll
    for (int ks = 0; ks < 8; ++ks) {
        bf16x8 af[2];
#pragma unroll
        for (int uf = 0; uf < 2; ++uf) {
            const int rowa = w * 32 + 16 * uf + lr;
            af[uf] = *(const bf16x8*)(ab + rowa * 256 + ks * 32 + lg * 8);
        }
#pragma unroll
        for (int of = 0; of < 4; ++of) {
            const int rowz = of * 16 + lr;
            const int off = rowz * 512 + ((ks * 64 + lg * 16) ^ ((rowz & 7) << 4));
            bf16x8 zb = *(const bf16x8*)((const char*)zct + off);
            acc[0][of] = __builtin_amdgcn_mfma_f32_16x16x32_bf16(af[0], zb, acc[0][of], 0, 0, 0);
            acc[1][of] = __builtin_amdgcn_mfma_f32_16x16x32_bf16(af[1], zb, acc[1][of], 0, 0, 0);
        }
    }

    // ---- epilogue: relu + store ----
    float* obt = out + ((size_t)(b * T + t)) * (V * O);
#pragma unroll
    for (int vf = 0; vf < 2; ++vf)
#pragma unroll
        for (int of = 0; of < 4; ++of)
#pragma unroll
            for (int j = 0; j < 4; ++j) {
                const int u = w * 32 + 16 * vf + lg * 4 + j;
                const int o = of * 16 + lr;
                const float r = acc[vf][of][j];
                obt[u * 64 + o] = r > 0.f ? r : 0.f;
            }
}

}  // namespace

extern "C" void kernel_launch(void* const* d_in, const int* in_sizes, int n_in,
                              void* d_out, int out_size, void* d_ws, size_t ws_size,
                              hipStream_t stream) {
    const float* x = (const float*)d_in[0];      // (B,T,V,F)
    const float* W = (const float*)d_in[1];      // (B,V,V)
    const float* Theta = (const float*)d_in[2];  // (3,F,O)
    float* outp = (float*)d_out;                 // (B,T,V,O)

    unsigned short* acat = (unsigned short*)d_ws;
    unsigned short* tht = (unsigned short*)((char*)d_ws + WS_THT_OFF);
    float* ldg = (float*)((char*)d_ws + WS_LDG_OFF);

    prep<<<B + 1, 256, 0, stream>>>(W, Theta, acat, tht, ldg);
    graph_conv_main<<<dim3(T, B), 256, 0, stream>>>(x, acat, tht, ldg, outp);
}

// Round 6
// 92.869 us; speedup vs baseline: 1.8775x; 1.3861x over previous
//
#include <hip/hip_runtime.h>

typedef __attribute__((ext_vector_type(8))) short bf16x8;
typedef __attribute__((ext_vector_type(4))) float f32x4;

namespace {

constexpr int B = 32, T = 128, V = 128, F = 64, O = 64;

// ws layout (bytes):
//   [acat_f bf16: B * (8 ks * 8 r2 * 64 lane) frags * 16B = 2 MiB]   fragment-major Acat
//   [tht_f  bf16: (2 ks * 12 nf * 64 lane) frags * 16B = 24 KiB]     fragment-major ThT
//   [ldg    f32 : B*V = 16 KiB]
constexpr size_t WS_THT_OFF = (size_t)B * 64 * 64 * 8 * 2;   // 2 MiB (in bytes)
constexpr size_t WS_LDG_OFF = WS_THT_OFF + 1536 * 8 * 2;     // +24 KiB

__device__ inline unsigned short f2bf(float f) {
    unsigned u = __builtin_bit_cast(unsigned, f);
    u += 0x7FFFu + ((u >> 16) & 1u);
    return (unsigned short)(u >> 16);
}

// ---------------- prep: fragment-major Acat/ThT, ldiag ----------------
__global__ __launch_bounds__(256) void prep(const float* __restrict__ W,
                                            const float* __restrict__ Theta,
                                            unsigned short* __restrict__ acat_f,
                                            unsigned short* __restrict__ tht_f,
                                            float* __restrict__ ldg) {
    const int tid = threadIdx.x;
    if (blockIdx.x == B) {
        // tht_f frag fi = ks*768 + nf*64 + lane; lane holds ThT[n = nf*16+lr][f = ks*32+lg*8 .. +8)
        // ThT rows n: [0,64) = Th0-Th2, [64,128) = Th1, [128,192) = Th2
        for (int i = 0; i < 6; ++i) {
            int fi = tid + i * 256;                 // [0,1536)
            int ks = fi / 768, rem = fi % 768;
            int nf = rem >> 6, lane = rem & 63;
            int n = nf * 16 + (lane & 15);
            int f0 = ks * 32 + (lane >> 4) * 8;
            unsigned short vals[8];
#pragma unroll
            for (int j = 0; j < 8; ++j) {
                int f = f0 + j;
                float v;
                if (n < 64)       v = Theta[f * 64 + n] - Theta[2 * 4096 + f * 64 + n];
                else if (n < 128) v = Theta[4096 + f * 64 + (n - 64)];
                else              v = Theta[2 * 4096 + f * 64 + (n - 128)];
                vals[j] = f2bf(v);
            }
            *(bf16x8*)(tht_f + (size_t)fi * 8) = *(bf16x8*)vals;
        }
        return;
    }
    const int b = blockIdx.x;
    const float* Wb = W + (size_t)b * V * V;
    __shared__ float Wl[V][V + 1];
    for (int i = 0; i < V * V / 256; ++i) {
        int idx = tid + i * 256;
        Wl[idx >> 7][idx & 127] = Wb[idx];
    }
    __syncthreads();
    if (tid < V) {
        float s = 0.f;
        for (int i = 0; i < V; ++i) s += Wl[i][tid];       // deg[u] = sum_i W[i][u]
        ldg[b * V + tid] = s - 1.0f - Wl[tid][tid];        // ldiag
    }
    // acat_f frag fi = ks*512 + r2*64 + lane; lane holds Acat[u = r2*16+lr][kv = ks*32+lg*8 .. +8)
    unsigned short* ab_f = acat_f + (size_t)b * 32768;
    for (int i = 0; i < 16; ++i) {
        int fi = tid + i * 256;                    // [0,4096)
        int ks = fi >> 9, rem = fi & 511;
        int r2 = rem >> 6, lane = rem & 63;
        int u = r2 * 16 + (lane & 15);
        int kv0 = ks * 32 + (lane >> 4) * 8;
        unsigned short vals[8];
#pragma unroll
        for (int j = 0; j < 8; ++j) {
            int kv = kv0 + j, v = kv & 127;
            float wv = Wl[v][u];
            float val = (v == u) ? 0.f : ((kv < 128) ? -wv : 2.f * wv * wv);
            vals[j] = f2bf(val);
        }
        *(bf16x8*)(ab_f + (size_t)fi * 8) = *(bf16x8*)vals;
    }
}

// ---------------- main: per (b,t); wave-local x staging; Z1->LDS, Z2 reuses regs+x-buffer ----------------
__global__ __launch_bounds__(256, 4) void graph_conv_main(
    const float* __restrict__ x, const unsigned short* __restrict__ acat_f,
    const unsigned short* __restrict__ tht_f, const float* __restrict__ ldg,
    float* __restrict__ out) {
    const int t = blockIdx.x, b = blockIdx.y;
    const int tid = threadIdx.x;
    const int lane = tid & 63, w = tid >> 6;
    const int lr = lane & 15, lg = lane >> 4;

    __shared__ __align__(16) unsigned short xsz[8192];  // 16KB: x slabs (4x4KB), later Z2 half
    __shared__ __align__(16) unsigned short zc1[8192];  // 16KB: Z1 half
    // total 32 KB -> 5 blocks/CU

    // ---- stage OWN 32-row slab, coalesced (no barrier: producer == consumer wave) ----
    const float* xbt = x + ((size_t)(b * T + t)) * (V * F);
    const float4* xslab = (const float4*)(xbt + w * 32 * 64);
    char* xbase = (char*)xsz + w * 4096;
#pragma unroll
    for (int i = 0; i < 8; ++i) {
        float4 q = xslab[i * 64 + lane];
        int f4 = i * 64 + lane;                    // float4 idx within slab [0,512)
        int row = f4 >> 4, c4 = f4 & 15;
        uint2 p;
        p.x = f2bf(q.x) | ((unsigned)f2bf(q.y) << 16);
        p.y = f2bf(q.z) | ((unsigned)f2bf(q.w) << 16);
        *(uint2*)(xbase + row * 128 + ((c4 * 8) ^ ((row & 7) << 4))) = p;
    }

    // ---- xa fragments from own slab ----
    bf16x8 xa[2][2];
#pragma unroll
    for (int vf = 0; vf < 2; ++vf) {
        int row = 16 * vf + lr;
#pragma unroll
        for (int ks = 0; ks < 2; ++ks)
            xa[vf][ks] = *(const bf16x8*)(xbase + row * 128 + ((ks * 64 + lg * 16) ^ ((row & 7) << 4)));
    }

    f32x4 acc[2][4], z[2][4];
#pragma unroll
    for (int vf = 0; vf < 2; ++vf)
#pragma unroll
        for (int of = 0; of < 4; ++of) {
            acc[vf][of] = (f32x4){0.f, 0.f, 0.f, 0.f};
            z[vf][of] = (f32x4){0.f, 0.f, 0.f, 0.f};
        }

    // ---- part 1: Zm (tht rows 0..63) -> acc, Z1 (rows 64..127) -> z; tb coalesced from global ----
#pragma unroll
    for (int ks = 0; ks < 2; ++ks)
#pragma unroll
        for (int nf = 0; nf < 8; ++nf) {
            bf16x8 tb = *(const bf16x8*)(tht_f + ((size_t)(ks * 12 + nf) * 64 + lane) * 8);
            if (nf < 4) {
                acc[0][nf] = __builtin_amdgcn_mfma_f32_16x16x32_bf16(xa[0][ks], tb, acc[0][nf], 0, 0, 0);
                acc[1][nf] = __builtin_amdgcn_mfma_f32_16x16x32_bf16(xa[1][ks], tb, acc[1][nf], 0, 0, 0);
            } else {
                z[0][nf - 4] = __builtin_amdgcn_mfma_f32_16x16x32_bf16(xa[0][ks], tb, z[0][nf - 4], 0, 0, 0);
                z[1][nf - 4] = __builtin_amdgcn_mfma_f32_16x16x32_bf16(xa[1][ks], tb, z[1][nf - 4], 0, 0, 0);
            }
        }

    // ---- diag(Z1) + write Z1 -> zc1 (fresh buffer; readers gated by barB) ----
    const float* ldb = ldg + b * V;
    f32x4 ldv[2];
#pragma unroll
    for (int vf = 0; vf < 2; ++vf) {
        ldv[vf] = *(const f32x4*)(ldb + w * 32 + 16 * vf + lg * 4);
#pragma unroll
        for (int of = 0; of < 4; ++of) acc[vf][of] += ldv[vf] * z[vf][of];
    }
#pragma unroll
    for (int vf = 0; vf < 2; ++vf) {
        int vcol = w * 32 + 16 * vf + lg * 4;
#pragma unroll
        for (int of = 0; of < 4; ++of) {
            int rowz = of * 16 + lr;
            f32x4 zv = z[vf][of];
            uint2 q;
            q.x = f2bf(zv[0]) | ((unsigned)f2bf(zv[1]) << 16);
            q.y = f2bf(zv[2]) | ((unsigned)f2bf(zv[3]) << 16);
            *(uint2*)((char*)zc1 + rowz * 256 + ((vcol * 2) ^ ((rowz & 7) << 4))) = q;
            z[vf][of] = (f32x4){0.f, 0.f, 0.f, 0.f};    // reuse for Z2
        }
    }

    // ---- part 2: Z2 (tht rows 128..191) into reused z regs ----
#pragma unroll
    for (int ks = 0; ks < 2; ++ks)
#pragma unroll
        for (int nf = 0; nf < 4; ++nf) {
            bf16x8 tb = *(const bf16x8*)(tht_f + ((size_t)(ks * 12 + 8 + nf) * 64 + lane) * 8);
            z[0][nf] = __builtin_amdgcn_mfma_f32_16x16x32_bf16(xa[0][ks], tb, z[0][nf], 0, 0, 0);
            z[1][nf] = __builtin_amdgcn_mfma_f32_16x16x32_bf16(xa[1][ks], tb, z[1][nf], 0, 0, 0);
        }

    // ---- diag(Z2) ----
#pragma unroll
    for (int vf = 0; vf < 2; ++vf) {
        f32x4 ld2 = 2.0f * ldv[vf] * ldv[vf];
#pragma unroll
        for (int of = 0; of < 4; ++of) acc[vf][of] += ld2 * z[vf][of];
    }

    __syncthreads();   // bar A: all waves done reading x slabs (xsz about to become Z2)

    // ---- write Z2 -> xsz (o-major half, same layout as zc1) ----
#pragma unroll
    for (int vf = 0; vf < 2; ++vf) {
        int vcol = w * 32 + 16 * vf + lg * 4;
#pragma unroll
        for (int of = 0; of < 4; ++of) {
            int rowz = of * 16 + lr;
            f32x4 zv = z[vf][of];
            uint2 q;
            q.x = f2bf(zv[0]) | ((unsigned)f2bf(zv[1]) << 16);
            q.y = f2bf(zv[2]) | ((unsigned)f2bf(zv[3]) << 16);
            *(uint2*)((char*)xsz + rowz * 256 + ((vcol * 2) ^ ((rowz & 7) << 4))) = q;
        }
    }
    __syncthreads();   // bar B: Z1+Z2 visible

    // ---- contraction: acc += Acat[u,0:256] @ [Z1;Z2]; af coalesced from fragment-major global ----
#pragma unroll
    for (int ks = 0; ks < 8; ++ks) {
        bf16x8 af[2];
#pragma unroll
        for (int uf = 0; uf < 2; ++uf)
            af[uf] = *(const bf16x8*)(acat_f +
                     (((size_t)b * 64 + ks * 8 + (w * 2 + uf)) * 64 + lane) * 8);
        const char* zsrc = (ks < 4) ? (const char*)zc1 : (const char*)xsz;
        const int kcol = (ks & 3) * 64 + lg * 16;
#pragma unroll
        for (int of = 0; of < 4; ++of) {
            int rowz = of * 16 + lr;
            bf16x8 zb = *(const bf16x8*)(zsrc + rowz * 256 + (kcol ^ ((rowz & 7) << 4)));
            acc[0][of] = __builtin_amdgcn_mfma_f32_16x16x32_bf16(af[0], zb, acc[0][of], 0, 0, 0);
            acc[1][of] = __builtin_amdgcn_mfma_f32_16x16x32_bf16(af[1], zb, acc[1][of], 0, 0, 0);
        }
    }

    // ---- epilogue: relu + store ----
    float* obt = out + ((size_t)(b * T + t)) * (V * O);
#pragma unroll
    for (int vf = 0; vf < 2; ++vf)
#pragma unroll
        for (int of = 0; of < 4; ++of)
#pragma unroll
            for (int j = 0; j < 4; ++j) {
                int u = w * 32 + 16 * vf + lg * 4 + j;
                int o = of * 16 + lr;
                float r = acc[vf][of][j];
                obt[u * 64 + o] = r > 0.f ? r : 0.f;
            }
}

}  // namespace

extern "C" void kernel_launch(void* const* d_in, const int* in_sizes, int n_in,
                              void* d_out, int out_size, void* d_ws, size_t ws_size,
                              hipStream_t stream) {
    const float* x = (const float*)d_in[0];      // (B,T,V,F)
    const float* W = (const float*)d_in[1];      // (B,V,V)
    const float* Theta = (const float*)d_in[2];  // (3,F,O)
    float* outp = (float*)d_out;                 // (B,T,V,O)

    unsigned short* acat_f = (unsigned short*)d_ws;
    unsigned short* tht_f = (unsigned short*)((char*)d_ws + WS_THT_OFF);
    float* ldg = (float*)((char*)d_ws + WS_LDG_OFF);

    prep<<<B + 1, 256, 0, stream>>>(W, Theta, acat_f, tht_f, ldg);
    graph_conv_main<<<dim3(T, B), 256, 0, stream>>>(x, acat_f, tht_f, ldg, outp);
}